// Round 1
// 204.008 us; speedup vs baseline: 1.0914x; 1.0914x over previous
//
#include <hip/hip_runtime.h>

#define B_ 512
#define S_ 512
#define E_ 128
#define H_ 100
#define T_ 64
#define V_ 100000
#define BS_ (B_*S_)

typedef __attribute__((ext_vector_type(8))) short bf16x8;
typedef __attribute__((ext_vector_type(4))) float f32x4;
typedef _Float16 h2 __attribute__((ext_vector_type(2)));
union U16x4 { uint4 u; bf16x8 s; };

__device__ __forceinline__ unsigned f2bf1(float x){
    unsigned u = __float_as_uint(x);
    return (u + 0x7FFFu + ((u>>16)&1u)) >> 16;
}
__device__ __forceinline__ float bf2f(unsigned short h){
    return __uint_as_float(((unsigned)h)<<16);
}
__device__ __forceinline__ float rfl_f(float x){
    return __uint_as_float(__builtin_amdgcn_readfirstlane(__float_as_uint(x)));
}
__device__ __forceinline__ unsigned addpack3(unsigned a, unsigned b, unsigned c){
    float lo = __uint_as_float(a<<16) + __uint_as_float(b<<16) + __uint_as_float(c<<16);
    float hi = __uint_as_float(a&0xFFFF0000u) + __uint_as_float(b&0xFFFF0000u)
             + __uint_as_float(c&0xFFFF0000u);
    return f2bf1(lo) | (f2bf1(hi)<<16);
}
__device__ __forceinline__ float fdot2h(unsigned u, h2 e, float c){
    h2 p; __builtin_memcpy(&p, &u, 4);
#if __has_builtin(__builtin_amdgcn_fdot2)
    return __builtin_amdgcn_fdot2(p, e, c, false);
#else
    return fmaf((float)p.x, (float)e.x, fmaf((float)p.y, (float)e.y, c));
#endif
}
// quad_perm DPP cross-lane (VALU path — NOT a DS op): xor1=[1,0,3,2], xor2=[2,3,0,1]
__device__ __forceinline__ float dpp_xor1(float x){
    return __int_as_float(__builtin_amdgcn_mov_dpp(__float_as_int(x), 0xB1, 0xF, 0xF, true));
}
__device__ __forceinline__ float dpp_xor2(float x){
    return __int_as_float(__builtin_amdgcn_mov_dpp(__float_as_int(x), 0x4E, 0xF, 0xF, true));
}

// ---------------------------------------------------------------------------
// prep_tbl: fp32 emb table -> bf16 copy.
// ---------------------------------------------------------------------------
__global__ __launch_bounds__(256) void prep_tbl(
    const float* __restrict__ tbl, uint2* __restrict__ tblh)
{
    int idx = blockIdx.x*256 + threadIdx.x;
    if (idx < (V_*E_)/4) {
        float4 v = ((const float4*)tbl)[idx];
        uint2 o;
        o.x = f2bf1(v.x) | (f2bf1(v.y)<<16);
        o.y = f2bf1(v.z) | (f2bf1(v.w)<<16);
        tblh[idx] = o;
    }
}

// ---------------------------------------------------------------------------
// prep_w: W1/W2 bf16 MFMA B-fragment images.
// ---------------------------------------------------------------------------
__global__ __launch_bounds__(64) void prep_w(
    const float* __restrict__ W1, const float* __restrict__ W2,
    uint4* __restrict__ W1f, uint4* __restrict__ W2f)
{
    const int idx = blockIdx.x*64 + threadIdx.x;
    if (idx < 7*4*64) {
        int lane = idx & 63, kt = (idx>>6)&3, nt = idx>>8;
        int n = nt*16 + (lane&15);
        int kb = kt*32 + (lane>>4)*8;
        unsigned wv[4];
        #pragma unroll
        for (int p = 0; p < 4; ++p) {
            float v0 = (n < H_) ? W1[(kb+2*p  )*H_ + n] : 0.f;
            float v1 = (n < H_) ? W1[(kb+2*p+1)*H_ + n] : 0.f;
            wv[p] = f2bf1(v0) | (f2bf1(v1) << 16);
        }
        W1f[idx] = make_uint4(wv[0],wv[1],wv[2],wv[3]);
    } else {
        int id2 = idx - 7*4*64;
        int lane = id2 & 63, kt = (id2>>6)&3, nt = id2>>8;
        int n = nt*16 + (lane&15);
        int kb = kt*32 + (lane>>4)*8;
        unsigned wv[4];
        #pragma unroll
        for (int p = 0; p < 4; ++p) {
            int k0 = kb+2*p, k1 = kb+2*p+1;
            float v0 = (k0 < H_) ? W2[k0*T_ + n] : 0.f;
            float v1 = (k1 < H_) ? W2[k1*T_ + n] : 0.f;
            wv[p] = f2bf1(v0) | (f2bf1(v1) << 16);
        }
        W2f[id2] = make_uint4(wv[0],wv[1],wv[2],wv[3]);
    }
}

// ---------------------------------------------------------------------------
// ROUND 17: producer/consumer wave specialization. 256 threads = 4 waves:
//   wid 0/1 = pure scan (fwd/bwd alpha-beta recursion), wid 2/3 = producer
//   (gathers + MLP MFMA + ring write + numerator). Handshake = LDS ring of 8
//   chunks/direction + monotonic LDS flags (release: lgkmcnt(0) before flag;
//   acquire: volatile poll + s_sleep). Removes the scan<->produce
//   serialization that capped the r16 kernel at VALUBusy 46% / 1 wave/SIMD.
// Also FIXES latent bwd offset bug: baseOf bwd = 496-16p (was 480-16p), so
//   bwd produce(p) covers exactly scan chunks {2p,2p+1} (t=256..511 complete,
//   no ring slot aliasing, numerator covers t=256..511 once).
// ---------------------------------------------------------------------------
__global__ __launch_bounds__(256, 2)
void fused_kernel(
    const int* __restrict__ inputs, const int* __restrict__ tags,
    const unsigned short* __restrict__ tblh,
    const float* __restrict__ b1, const float* __restrict__ b2,
    const uint4* __restrict__ W1f, const uint4* __restrict__ W2f,
    const float* __restrict__ start_trans, const float* __restrict__ end_trans,
    const float* __restrict__ trans, float* __restrict__ out)
{
    __shared__ uint4 sW1f[1792];                         // 28 KB
    __shared__ uint4 sW2f[1024];                         // 16 KB
    __shared__ __align__(16) unsigned short ring[2][8][512];  // 16 KB
    __shared__ uint4 sA2[2][256];                        // 8 KB
    __shared__ __align__(16) _Float16 pbufH[2][T_];
    __shared__ float pubB[T_];
    __shared__ float fnum[2];
    __shared__ int   icnt[2];
    __shared__ float lsB_sh;
    __shared__ int   prodF[2];   // chunks produced (monotonic)
    __shared__ int   consF[2];   // chunks whose LDS data is fully consumed

    const int b   = blockIdx.x;
    const int tid = threadIdx.x;
    const int wid = tid >> 6;
    const int j   = tid & 63;
    const int d   = wid & 1;             // direction: 0=fwd, 1=bwd
    const bool isProd = wid >= 2;
    const int col = j & 15;
    const int hi  = j >> 4;
    const int rowin = hi * 4;
    const int* tags_b = tags + b*S_;
    const int* in_b   = inputs + (size_t)b*S_*3;

    for (int i = tid; i < 1792; i += 256) sW1f[i] = W1f[i];
    for (int i = tid; i < 1024; i += 256) sW2f[i] = W2f[i];
    if (tid == 0) { prodF[0] = prodF[1] = 0; consF[0] = consF[1] = 0; }

    // ---- mask ballots for THIS direction's half ----
    unsigned long long mball[4];
    #pragma unroll
    for (int g4 = 0; g4 < 4; ++g4) {
        int t = (d*4 + g4)*64 + j;
        int a0 = in_b[t*3+0], a1 = in_b[t*3+1], a2 = in_b[t*3+2];
        mball[g4] = __ballot((a0 | a1 | a2) != 0);
    }
    if (isProd) {
        int cnt = 0;
        #pragma unroll
        for (int g4 = 0; g4 < 4; ++g4) cnt += __popcll(mball[g4]);
        if (j == 0) icnt[d] = cnt;
    }

    __syncthreads();

    auto baseOf = [&](int p){ return d ? (496 - 16*p) : 16*p; };

    float aF = 0.f, lsF = 0.f;   // fwd scan result, consumed in merge by wid 0

    if (isProd) {
        // ================= PRODUCER =================
        float bv1[7], bv2[4];
        #pragma unroll
        for (int nt = 0; nt < 7; ++nt) { int n = nt*16+col; bv1[nt] = (n < H_) ? b1[n] : 0.f; }
        #pragma unroll
        for (int nt2 = 0; nt2 < 4; ++nt2) bv2[nt2] = b2[nt2*16+col];

        auto loadIdx = [&](int p, int& x, int& y, int& z){
            int t = baseOf(p) + col;
            x = in_b[t*3 + 0]; y = in_b[t*3 + 1]; z = in_b[t*3 + 2];
        };
        auto issueGathers = [&](int i0, int i1, int i2, uint4* g){
            const unsigned short* tr0 = tblh + (size_t)i0*E_;
            const unsigned short* tr1 = tblh + (size_t)i1*E_;
            const unsigned short* tr2 = tblh + (size_t)i2*E_;
            #pragma unroll
            for (int kt = 0; kt < 4; ++kt) {
                int off = kt*32 + hi*8;
                g[kt*3+0] = *(const uint4*)(tr0 + off);
                g[kt*3+1] = *(const uint4*)(tr1 + off);
                g[kt*3+2] = *(const uint4*)(tr2 + off);
            }
        };

        uint4 g[12];
        int i0, i1, i2;
        float np = 0.f;
        loadIdx(0, i0, i1, i2);
        issueGathers(i0, i1, i2, g);

        for (int p = 0; p < 16; ++p) {
            // ---- pack gathered rows -> MFMA A frags ----
            U16x4 a4[4];
            #pragma unroll
            for (int kt = 0; kt < 4; ++kt)
                a4[kt].u = make_uint4(
                    addpack3(g[kt*3+0].x, g[kt*3+1].x, g[kt*3+2].x),
                    addpack3(g[kt*3+0].y, g[kt*3+1].y, g[kt*3+2].y),
                    addpack3(g[kt*3+0].z, g[kt*3+1].z, g[kt*3+2].z),
                    addpack3(g[kt*3+0].w, g[kt*3+1].w, g[kt*3+2].w));
            // prefetch next tile's gathers under the MFMA/pack work below
            if (p < 15) { loadIdx(p+1, i0, i1, i2); issueGathers(i0, i1, i2, g); }

            // ---- layer 1 MFMA + tanh ----
            f32x4 acc1[7];
            #pragma unroll
            for (int nt = 0; nt < 7; ++nt) {
                f32x4 c; c[0]=bv1[nt]; c[1]=bv1[nt]; c[2]=bv1[nt]; c[3]=bv1[nt];
                #pragma unroll
                for (int k = 0; k < 4; ++k) {
                    U16x4 bfr; bfr.u = sW1f[(nt*4+k)*64 + j];
                    c = __builtin_amdgcn_mfma_f32_16x16x32_bf16(a4[k].s, bfr.s, c, 0,0,0);
                }
                acc1[nt] = c;
            }
            #pragma unroll
            for (int nt = 0; nt < 7; ++nt)
                #pragma unroll
                for (int rr = 0; rr < 4; ++rr) {
                    float x = acc1[nt][rr];
                    acc1[nt][rr] = 1.f - 2.f/(__expf(2.f*x)+1.f);
                }

            // ---- repack h as layer-2 A frags in sA2 ----
            if (j >= 32) sA2[d][3*64 + j] = make_uint4(0,0,0,0);
            unsigned short* A2h = (unsigned short*)sA2[d];
            #pragma unroll
            for (int nt = 0; nt < 7; ++nt)
                #pragma unroll
                for (int rr = 0; rr < 4; ++rr) {
                    int k2 = nt*16 + col;
                    int kt2 = k2 >> 5, g2 = (k2>>3)&3, i2v = k2&7;
                    int u4idx = kt2*64 + g2*16 + (rowin + rr);
                    A2h[u4idx*8 + i2v] = (unsigned short)f2bf1(acc1[nt][rr]);
                }
            __builtin_amdgcn_wave_barrier();

            U16x4 a2[4];
            #pragma unroll
            for (int k = 0; k < 4; ++k) a2[k].u = sA2[d][k*64 + j];
            __builtin_amdgcn_wave_barrier();

            // ---- layer 2 MFMA -> em tile in tbuf (stride-72 conflict-free) ----
            unsigned short* tbuf = (unsigned short*)sA2[d];
            #pragma unroll
            for (int nt2 = 0; nt2 < 4; ++nt2) {
                f32x4 c; c[0]=bv2[nt2]; c[1]=bv2[nt2]; c[2]=bv2[nt2]; c[3]=bv2[nt2];
                #pragma unroll
                for (int k = 0; k < 4; ++k) {
                    U16x4 bfr; bfr.u = sW2f[(nt2*4+k)*64 + j];
                    c = __builtin_amdgcn_mfma_f32_16x16x32_bf16(a2[k].s, bfr.s, c, 0,0,0);
                }
                #pragma unroll
                for (int rr = 0; rr < 4; ++rr)
                    tbuf[(rowin+rr)*72 + nt2*16 + col] = (unsigned short)f2bf1(c[rr]);
            }
            __builtin_amdgcn_wave_barrier();

            // ---- flow control: chunks 2p,2p+1 overwrite chunks 2p-8,2p-7 ----
            if (p >= 4) {
                volatile int* cf = &consF[d];
                while (*cf < 2*p - 7) __builtin_amdgcn_s_sleep(1);
                __asm__ volatile("" ::: "memory");
            }
            // ---- ring write ----
            {
                const int rl = j >> 2;
                const int ch = (j & 3) * 2;
                const uint4* t4 = (const uint4*)tbuf;
                uint4 u0 = t4[rl*9 + ch];
                uint4 u1 = t4[rl*9 + ch + 1];
                int row = baseOf(p) + rl;
                int grp = row >> 3;
                int kidx = d ? (63 - grp) : grp;
                uint4* dst = (uint4*)&ring[d][kidx & 7][(row & 7)*64];
                dst[ch]   = u0;
                dst[ch+1] = u1;
            }
            // release: data drained before flag store
            __asm__ volatile("s_waitcnt lgkmcnt(0)" ::: "memory");
            if (j == 0) prodF[d] = 2*p + 2;
            __builtin_amdgcn_wave_barrier();

            // ---- numerator scoring for this 16-row tile ----
            if (j < 16) {
                int t = baseOf(p) + j;
                if (t >= 1) {
                    int word = (t >> 6) - d*4;
                    if ((mball[word] >> (t & 63)) & 1ull) {
                        int tp = tags_b[t-1], tc = tags_b[t];
                        int grp = t >> 3;
                        int kidx = d ? (63 - grp) : grp;
                        np += trans[tp*T_ + tc] + bf2f(ring[d][kidx & 7][(t & 7)*64 + tc]);
                    }
                }
            }
            if (d == 0 && p == 0 && j == 0) {
                int tag0 = tags_b[0];
                np += start_trans[tag0] + bf2f(ring[0][0][tag0]);
            }
        }

        #pragma unroll
        for (int off = 32; off >= 1; off >>= 1) np += __shfl_xor(np, off, 64);
        if (j == 0) fnum[d] = np;

    } else {
        // ================= CONSUMER (scan) =================
        const int qg  = j >> 2;
        const int qm  = j & 3;
        const bool qb0 = (j & 1) != 0;
        const bool qb1 = (j & 2) != 0;

        // E slice in fp16: 4 outputs (quad) x 16 inputs (slot) = 32 h2
        h2 E2[32];
        #pragma unroll
        for (int o = 0; o < 4; ++o)
            #pragma unroll
            for (int i = 0; i < 8; ++i) {
                int r0, c0, r1, c1;
                if (d == 0) { r0 = 16*qm + 2*i; c0 = 4*qg + o; r1 = r0 + 1; c1 = c0; }
                else        { r0 = 4*qg + o; c0 = 16*qm + 2*i; r1 = r0; c1 = c0 + 1; }
                h2 e; e.x = (_Float16)__expf(trans[r0*T_ + c0]);
                      e.y = (_Float16)__expf(trans[r1*T_ + c1]);
                E2[o*8 + i] = e;
            }
        if (d == 0) mball[0] &= ~1ull;   // t=0 handled in init

        volatile int* pf = &prodF[d];
        while (*pf < 1) __builtin_amdgcn_s_sleep(1);
        __asm__ volatile("" ::: "memory");

        float a, ls;
        if (d == 0) {
            float x0v = start_trans[j] + bf2f(ring[0][0][j]);
            ls = rfl_f(x0v);
            a  = __expf(x0v - ls);
        } else {
            a  = __expf(end_trans[j]);
            ls = 0.f;
        }
        float eg[8];
        #pragma unroll
        for (int s = 0; s < 8; ++s)
            eg[s] = __expf(bf2f(ring[d][0][(d ? (7-s) : s)*64 + j]));

        for (int k = 0; k < 32; ++k) {
            unsigned short raw16[8];
            if (k < 31) {
                // acquire chunk k+1
                while (*pf < k + 2) __builtin_amdgcn_s_sleep(1);
                __asm__ volatile("" ::: "memory");
                const unsigned short* nxt = ring[d][(k+1) & 7];
                #pragma unroll
                for (int s = 0; s < 8; ++s)
                    raw16[s] = nxt[(d ? (7-s) : s)*64 + j];
                __asm__ volatile("s_waitcnt lgkmcnt(0)" ::: "memory");
                if (j == 0) consF[d] = k + 1;   // chunks <=k free; k+1 in regs
            }
            const int ag = d ? (63 - k) : k;
            const unsigned mg = (unsigned)((mball[(ag>>3) - d*4] >> ((ag&7)*8)) & 0xFFull);

            #pragma unroll
            for (int s = 0; s < 8; ++s) {
                float wv = (d == 0) ? a : (eg[s] * a);
                pbufH[d][j] = (_Float16)(wv * 0.015625f);
                __builtin_amdgcn_wave_barrier();
                float sc   = rfl_f(a);
                float sinv = __builtin_amdgcn_rcpf(sc);
                float logs = __logf(sc);
                float keep = a * sinv;
                float dmul = ((d == 0) ? (eg[s] * sinv) : sinv) * 64.0f;

                // 2x b128: this lane's 16-input slice
                const uint4* ph = (const uint4*)pbufH[d];
                uint4 U0 = ph[2*qm];
                uint4 U1 = ph[2*qm + 1];
                float p0, p1, p2, p3;
                p0 = fdot2h(U0.x, E2[ 0], 0.f);  p0 = fdot2h(U0.y, E2[ 1], p0);
                p0 = fdot2h(U0.z, E2[ 2], p0);   p0 = fdot2h(U0.w, E2[ 3], p0);
                p0 = fdot2h(U1.x, E2[ 4], p0);   p0 = fdot2h(U1.y, E2[ 5], p0);
                p0 = fdot2h(U1.z, E2[ 6], p0);   p0 = fdot2h(U1.w, E2[ 7], p0);
                p1 = fdot2h(U0.x, E2[ 8], 0.f);  p1 = fdot2h(U0.y, E2[ 9], p1);
                p1 = fdot2h(U0.z, E2[10], p1);   p1 = fdot2h(U0.w, E2[11], p1);
                p1 = fdot2h(U1.x, E2[12], p1);   p1 = fdot2h(U1.y, E2[13], p1);
                p1 = fdot2h(U1.z, E2[14], p1);   p1 = fdot2h(U1.w, E2[15], p1);
                p2 = fdot2h(U0.x, E2[16], 0.f);  p2 = fdot2h(U0.y, E2[17], p2);
                p2 = fdot2h(U0.z, E2[18], p2);   p2 = fdot2h(U0.w, E2[19], p2);
                p2 = fdot2h(U1.x, E2[20], p2);   p2 = fdot2h(U1.y, E2[21], p2);
                p2 = fdot2h(U1.z, E2[22], p2);   p2 = fdot2h(U1.w, E2[23], p2);
                p3 = fdot2h(U0.x, E2[24], 0.f);  p3 = fdot2h(U0.y, E2[25], p3);
                p3 = fdot2h(U0.z, E2[26], p3);   p3 = fdot2h(U0.w, E2[27], p3);
                p3 = fdot2h(U1.x, E2[28], p3);   p3 = fdot2h(U1.y, E2[29], p3);
                p3 = fdot2h(U1.z, E2[30], p3);   p3 = fdot2h(U1.w, E2[31], p3);

                // quad reduce-scatter via DPP: lane j ends with y_j
                float t0 = qb1 ? p2 : p0;
                float t1 = qb1 ? p3 : p1;
                float s0 = qb1 ? p0 : p2;
                float s1 = qb1 ? p1 : p3;
                t0 += dpp_xor2(s0);
                t1 += dpp_xor2(s1);
                float tt = qb0 ? t1 : t0;
                float ss = qb0 ? t0 : t1;
                float y  = tt + dpp_xor1(ss);

                float cand = y * dmul;
                const int bit = (d == 0) ? s : (7 - s);
                a = ((mg >> bit) & 1u) ? cand : keep;
                ls += logs;
                __builtin_amdgcn_wave_barrier();
            }
            if (k < 31) {
                #pragma unroll
                for (int s = 0; s < 8; ++s) eg[s] = __expf(bf2f(raw16[s]));
            }
        }

        if (d == 1) {
            pubB[j] = a;
            if (j == 0) lsB_sh = ls;
        } else {
            aF = a; lsF = ls;
        }
    }

    __syncthreads();

    // ---- merge (fwd scan wave) ----
    if (wid == 0) {
        float x = aF * pubB[j];
        #pragma unroll
        for (int off = 32; off >= 1; off >>= 1) x += __shfl_xor(x, off, 64);
        int mcount = icnt[0] + icnt[1];
        int se = mcount - 1; if (se < 0) se = 0;
        const int last_tag = tags_b[se];
        float numer = fnum[0] + fnum[1] + end_trans[last_tag];
        if (j == 0) out[b] = lsF + lsB_sh + __logf(x) - numer;
    }
}

// ---------------------------------------------------------------------------
extern "C" void kernel_launch(void* const* d_in, const int* in_sizes, int n_in,
                              void* d_out, int out_size, void* d_ws, size_t ws_size,
                              hipStream_t stream) {
    const int*   inputs      = (const int*)  d_in[0];
    const int*   tags        = (const int*)  d_in[1];
    const float* emb_table   = (const float*)d_in[2];
    const float* W1          = (const float*)d_in[3];
    const float* b1          = (const float*)d_in[4];
    const float* W2          = (const float*)d_in[5];
    const float* b2          = (const float*)d_in[6];
    const float* start_trans = (const float*)d_in[7];
    const float* end_trans   = (const float*)d_in[8];
    const float* transitions = (const float*)d_in[9];
    float* out = (float*)d_out;

    // ws: tblh bf16 (25.6 MB) | W1f (28 KB) | W2f (16 KB)
    unsigned short* tblh = (unsigned short*)d_ws;
    uint4* W1f = (uint4*)((char*)d_ws + (size_t)V_*E_*2);
    uint4* W2f = W1f + 7*4*64;

    prep_tbl<<<dim3((V_*E_/4 + 255)/256), dim3(256), 0, stream>>>(emb_table, (uint2*)tblh);
    prep_w<<<dim3((7*4*64 + 4*4*64)/64), dim3(64), 0, stream>>>(W1, W2, W1f, W2f);
    fused_kernel<<<dim3(B_), dim3(256), 0, stream>>>(
        inputs, tags, tblh, b1, b2, W1f, W2f,
        start_trans, end_trans, transitions, out);
}